// Round 5
// baseline (358.507 us; speedup 1.0000x reference)
//
#include <hip/hip_runtime.h>
#include <math.h>

#define B_N 2048
#define L_N 64
#define D_N 256   // EMBED_DIM
#define U_N 512   // UNITS

typedef __attribute__((ext_vector_type(8))) short bf16x8;   // 8 bf16 = 4 VGPRs
typedef __attribute__((ext_vector_type(4))) float f32x4;    // MFMA 16x16 acc

__device__ __forceinline__ float fast_tanh(float x) {
    float e = __expf(2.0f * x);
    return 1.0f - 2.0f / (e + 1.0f);
}
// fp32 -> bf16 round-to-nearest-even
__device__ __forceinline__ ushort f2bf(float x) {
    uint b = __float_as_uint(x);
    uint r = (b + 0x7FFF + ((b >> 16) & 1)) >> 16;
    return (ushort)r;
}
__device__ __forceinline__ float bf2f(ushort u) {
    uint v = ((uint)u) << 16;
    return __uint_as_float(v);
}

// ---------------------------------------------------------------------------
// K0: pack W1 [256,512] and W2 [512,512] fp32 -> bf16 MFMA B-fragment order.
// chunk g = (ntg*KS + ks)*64 + lane holds W[ks*32 + (lane>>4)*8 + j][ntg*16 + (lane&15)]
// ---------------------------------------------------------------------------
__global__ __launch_bounds__(256) void pack_weights(
    const float* __restrict__ W1, const float* __restrict__ W2,
    ushort* __restrict__ W1p, ushort* __restrict__ W2p)
{
    ushort tmp[8];
    if (blockIdx.x < 64) {
        int g = blockIdx.x * 256 + threadIdx.x;      // 0..16383
        int ntg = g >> 9, ks = (g >> 6) & 7, lane = g & 63;
        int n  = ntg * 16 + (lane & 15);
        int kb = ks * 32 + (lane >> 4) * 8;
#pragma unroll
        for (int j = 0; j < 8; ++j) tmp[j] = f2bf(W1[(kb + j) * U_N + n]);
        *(uint4*)&W1p[(size_t)g * 8] = *(uint4*)tmp;
    } else {
        int g = (blockIdx.x - 64) * 256 + threadIdx.x;  // 0..32767
        int ntg = g >> 10, ks = (g >> 6) & 15, lane = g & 63;
        int n  = ntg * 16 + (lane & 15);
        int kb = ks * 32 + (lane >> 4) * 8;
#pragma unroll
        for (int j = 0; j < 8; ++j) tmp[j] = f2bf(W2[(kb + j) * U_N + n]);
        *(uint4*)&W2p[(size_t)g * 8] = *(uint4*)tmp;
    }
}

// ---------------------------------------------------------------------------
// K1: ph = hidden @ W2 + b1 + b2 via bf16 MFMA, stored bf16.
// grid (B/16, U/128) = (128,4) = 512 blocks (2/CU). Wave: 32 u (2 n-tiles).
// ---------------------------------------------------------------------------
__global__ __launch_bounds__(256) void proj_h_mfma(
    const float* __restrict__ hidden, const ushort* __restrict__ W2p,
    const float* __restrict__ b1, const float* __restrict__ b2,
    ushort* __restrict__ ph)
{
    __shared__ ushort As[16 * 512];   // 16 KB

    const int t  = threadIdx.x;
    const int b0 = blockIdx.x * 16;
    const int u0 = blockIdx.y * 128;

    // stage hidden 16x512 fp32 -> bf16 (1024 chunks of 8, 4/thread), swizzled
#pragma unroll
    for (int i = 0; i < 4; ++i) {
        int f = t + i * 256;
        int m = f >> 6, c = f & 63;
        float4 x0 = *(const float4*)&hidden[(b0 + m) * U_N + c * 8];
        float4 x1 = *(const float4*)&hidden[(b0 + m) * U_N + c * 8 + 4];
        ushort tmp[8] = {f2bf(x0.x), f2bf(x0.y), f2bf(x0.z), f2bf(x0.w),
                         f2bf(x1.x), f2bf(x1.y), f2bf(x1.z), f2bf(x1.w)};
        *(uint4*)&As[(m * 64 + (c ^ (m & 7))) * 8] = *(uint4*)tmp;
    }
    __syncthreads();

    const int w = t >> 6, lane = t & 63;
    const int ml = lane & 15, q = lane >> 4;

    f32x4 acc[2];
#pragma unroll
    for (int nt = 0; nt < 2; ++nt) acc[nt] = (f32x4){0.f, 0.f, 0.f, 0.f};

    for (int ks = 0; ks < 16; ++ks) {
        int c = ks * 4 + q;
        bf16x8 a = *(const bf16x8*)&As[(ml * 64 + (c ^ (ml & 7))) * 8];
        bf16x8 bb[2];
#pragma unroll
        for (int nt = 0; nt < 2; ++nt) {
            int ntg = blockIdx.y * 8 + w * 2 + nt;
            bb[nt] = *(const bf16x8*)&W2p[(size_t)((ntg * 16 + ks) * 64 + lane) * 8];
        }
#pragma unroll
        for (int nt = 0; nt < 2; ++nt)
            acc[nt] = __builtin_amdgcn_mfma_f32_16x16x32_bf16(a, bb[nt], acc[nt], 0, 0, 0);
    }

    // C layout: n = nt*16 + ml (col), m = q*4 + r (row)
#pragma unroll
    for (int nt = 0; nt < 2; ++nt) {
        int n = u0 + (w * 2 + nt) * 16 + ml;
        float bias = b1[n] + b2[n];
#pragma unroll
        for (int r = 0; r < 4; ++r)
            ph[(size_t)(b0 + q * 4 + r) * U_N + n] = f2bf(acc[nt][r] + bias);
    }
}

// ---------------------------------------------------------------------------
// K2: per-batch fused attention, bf16 MFMA, occupancy-lean.
// Wave strip 128 u split into FOUR 32-u chunks: acc[4][2]=32 AGPR, bf[2]=8,
// epilogue folded per-chunk. Combined arch+acc budget targeted <= 128 so
// __launch_bounds__(256,4) holds 4 waves/SIMD resident WITHOUT spilling
// (R3's spill: structure needed 192 under a 128 cap; this needs ~110).
// ---------------------------------------------------------------------------
__global__ __launch_bounds__(256, 4) void attn_kernel(
    const float* __restrict__ features, const ushort* __restrict__ W1p,
    const float* __restrict__ V, const float* __restrict__ bV,
    const ushort* __restrict__ ph, float* __restrict__ out)
{
    __shared__ ushort As[64 * 256];   // 32 KB, chunk (m,c) at m*32 + (c ^ (m&31))
    __shared__ float lpart[4][64];
    __shared__ float wls[64];

    const int b    = blockIdx.x;
    const int t    = threadIdx.x;
    const int w    = t >> 6;
    const int lane = t & 63;
    const int ml   = lane & 15;
    const int q    = lane >> 4;
    const float* fb = features + (size_t)b * (L_N * D_N);

    // stage features -> bf16 swizzled LDS (2048 chunks, 8/thread)
#pragma unroll
    for (int i = 0; i < 8; ++i) {
        int f = t + i * 256;
        int m = f >> 5, c = f & 31;
        float4 x0 = *(const float4*)&fb[m * D_N + c * 8];
        float4 x1 = *(const float4*)&fb[m * D_N + c * 8 + 4];
        ushort tmp[8] = {f2bf(x0.x), f2bf(x0.y), f2bf(x0.z), f2bf(x0.w),
                         f2bf(x1.x), f2bf(x1.y), f2bf(x1.z), f2bf(x1.w)};
        *(uint4*)&As[(m * 32 + (c ^ (m & 31))) * 8] = *(uint4*)tmp;
    }
    __syncthreads();

    for (int uc = 0; uc < 4; ++uc) {
        f32x4 acc[4][2];
#pragma unroll
        for (int mt = 0; mt < 4; ++mt)
#pragma unroll
            for (int nt = 0; nt < 2; ++nt)
                acc[mt][nt] = (f32x4){0.f, 0.f, 0.f, 0.f};

        for (int ks = 0; ks < 8; ++ks) {
            bf16x8 a[4];
#pragma unroll
            for (int mt = 0; mt < 4; ++mt) {
                int m = mt * 16 + ml;
                int c = ks * 4 + q;
                a[mt] = *(const bf16x8*)&As[(m * 32 + (c ^ (m & 31))) * 8];
            }
            bf16x8 bf[2];
#pragma unroll
            for (int nt = 0; nt < 2; ++nt) {
                int chunk = ((w * 8 + uc * 2 + nt) * 8 + ks) * 64 + lane;
                bf[nt] = *(const bf16x8*)&W1p[(size_t)chunk * 8];
            }
#pragma unroll
            for (int nt = 0; nt < 2; ++nt)
#pragma unroll
                for (int mt = 0; mt < 4; ++mt)
                    acc[mt][nt] = __builtin_amdgcn_mfma_f32_16x16x32_bf16(
                        a[mt], bf[nt], acc[mt][nt], 0, 0, 0);
        }

        // epilogue for this 32-u chunk: tanh(C + ph) . V, n-lane reduce, fold.
        // D layout: n = nt*16 + ml, m = mt*16 + q*4 + r
        float lp[16];
#pragma unroll
        for (int j = 0; j < 16; ++j) lp[j] = 0.f;
#pragma unroll
        for (int nt = 0; nt < 2; ++nt) {
            int n = w * 128 + uc * 32 + nt * 16 + ml;
            float phv = bf2f(ph[(size_t)b * U_N + n]);
            float vv  = V[n];
#pragma unroll
            for (int mt = 0; mt < 4; ++mt)
#pragma unroll
                for (int r = 0; r < 4; ++r) {
                    float s = fast_tanh(acc[mt][nt][r] + phv);
                    lp[mt * 4 + r] = fmaf(s, vv, lp[mt * 4 + r]);
                }
        }
#pragma unroll
        for (int off = 1; off <= 8; off <<= 1)
#pragma unroll
            for (int j = 0; j < 16; ++j)
                lp[j] += __shfl_xor(lp[j], off);
        if (ml == 0) {
#pragma unroll
            for (int mt = 0; mt < 4; ++mt)
#pragma unroll
                for (int r = 0; r < 4; ++r) {
                    int m = mt * 16 + q * 4 + r;
                    if (uc == 0) lpart[w][m] = lp[mt * 4 + r];
                    else         lpart[w][m] += lp[mt * 4 + r];
                }
        }
    }
    __syncthreads();

    if (t < 64) {
        float lsum = bV[0] + lpart[0][t] + lpart[1][t] + lpart[2][t] + lpart[3][t];
        float mx = lsum;
#pragma unroll
        for (int off = 32; off > 0; off >>= 1)
            mx = fmaxf(mx, __shfl_xor(mx, off));
        float e = __expf(lsum - mx);
        float ssum = e;
#pragma unroll
        for (int off = 32; off > 0; off >>= 1)
            ssum += __shfl_xor(ssum, off);
        float wt = e / ssum;
        wls[t] = wt;
        out[(size_t)B_N * D_N + (size_t)b * L_N + t] = wt;
    }
    __syncthreads();

    float ctx = 0.f;
#pragma unroll 16
    for (int l = 0; l < L_N; ++l) {
        ushort u = As[(l * 32 + ((t >> 3) ^ (l & 31))) * 8 + (t & 7)];
        ctx = fmaf(wls[l], bf2f(u), ctx);
    }
    out[(size_t)b * D_N + t] = ctx;
}

// ---------------------------------------------------------------------------
extern "C" void kernel_launch(void* const* d_in, const int* in_sizes, int n_in,
                              void* d_out, int out_size, void* d_ws, size_t ws_size,
                              hipStream_t stream) {
    const float* features = (const float*)d_in[0];
    const float* hidden   = (const float*)d_in[1];
    const float* W1       = (const float*)d_in[2];
    const float* b1       = (const float*)d_in[3];
    const float* W2       = (const float*)d_in[4];
    const float* b2       = (const float*)d_in[5];
    const float* V        = (const float*)d_in[6];
    const float* bV       = (const float*)d_in[7];
    float* out = (float*)d_out;

    // ws: ph bf16 2 MB @0 | W1p 256 KB @2M | W2p 512 KB @2.25M
    ushort* ph  = (ushort*)d_ws;
    ushort* W1p = (ushort*)((char*)d_ws + (size_t)B_N * U_N * 2);
    ushort* W2p = (ushort*)((char*)d_ws + (size_t)B_N * U_N * 2 + (size_t)D_N * U_N * 2);

    pack_weights<<<192, 256, 0, stream>>>(W1, W2, W1p, W2p);
    proj_h_mfma<<<dim3(B_N / 16, U_N / 128), 256, 0, stream>>>(hidden, W2p, b1, b2, ph);
    attn_kernel<<<B_N, 256, 0, stream>>>(features, W1p, V, bV, ph, out);
}

// Round 6
// 335.940 us; speedup vs baseline: 1.0672x; 1.0672x over previous
//
#include <hip/hip_runtime.h>
#include <math.h>

#define B_N 2048
#define L_N 64
#define D_N 256   // EMBED_DIM
#define U_N 512   // UNITS

typedef __attribute__((ext_vector_type(8))) short bf16x8;   // 8 bf16 = 4 VGPRs
typedef __attribute__((ext_vector_type(4))) float f32x4;    // MFMA 16x16 acc

__device__ __forceinline__ float fast_tanh(float x) {
    float e = __expf(2.0f * x);
    return 1.0f - 2.0f / (e + 1.0f);
}
// fp32 -> bf16 round-to-nearest-even
__device__ __forceinline__ ushort f2bf(float x) {
    uint b = __float_as_uint(x);
    uint r = (b + 0x7FFF + ((b >> 16) & 1)) >> 16;
    return (ushort)r;
}
__device__ __forceinline__ float bf2f(ushort u) {
    uint v = ((uint)u) << 16;
    return __uint_as_float(v);
}

// ---------------------------------------------------------------------------
// K0: pack W1 [256,512] and W2 [512,512] fp32 -> bf16 MFMA B-fragment order.
// chunk g = (ntg*KS + ks)*64 + lane holds W[ks*32 + (lane>>4)*8 + j][ntg*16 + (lane&15)]
// ---------------------------------------------------------------------------
__global__ __launch_bounds__(256) void pack_weights(
    const float* __restrict__ W1, const float* __restrict__ W2,
    ushort* __restrict__ W1p, ushort* __restrict__ W2p)
{
    ushort tmp[8];
    if (blockIdx.x < 64) {
        int g = blockIdx.x * 256 + threadIdx.x;      // 0..16383
        int ntg = g >> 9, ks = (g >> 6) & 7, lane = g & 63;
        int n  = ntg * 16 + (lane & 15);
        int kb = ks * 32 + (lane >> 4) * 8;
#pragma unroll
        for (int j = 0; j < 8; ++j) tmp[j] = f2bf(W1[(kb + j) * U_N + n]);
        *(uint4*)&W1p[(size_t)g * 8] = *(uint4*)tmp;
    } else {
        int g = (blockIdx.x - 64) * 256 + threadIdx.x;  // 0..32767
        int ntg = g >> 10, ks = (g >> 6) & 15, lane = g & 63;
        int n  = ntg * 16 + (lane & 15);
        int kb = ks * 32 + (lane >> 4) * 8;
#pragma unroll
        for (int j = 0; j < 8; ++j) tmp[j] = f2bf(W2[(kb + j) * U_N + n]);
        *(uint4*)&W2p[(size_t)g * 8] = *(uint4*)tmp;
    }
}

// ---------------------------------------------------------------------------
// K1: ph = hidden @ W2 + b1 + b2 via bf16 MFMA, stored bf16.
// grid (B/16, U/128) = (128,4) = 512 blocks (2/CU). Wave: 32 u (2 n-tiles).
// ---------------------------------------------------------------------------
__global__ __launch_bounds__(256) void proj_h_mfma(
    const float* __restrict__ hidden, const ushort* __restrict__ W2p,
    const float* __restrict__ b1, const float* __restrict__ b2,
    ushort* __restrict__ ph)
{
    __shared__ ushort As[16 * 512];   // 16 KB

    const int t  = threadIdx.x;
    const int b0 = blockIdx.x * 16;
    const int u0 = blockIdx.y * 128;

    // stage hidden 16x512 fp32 -> bf16 (1024 chunks of 8, 4/thread), swizzled
#pragma unroll
    for (int i = 0; i < 4; ++i) {
        int f = t + i * 256;
        int m = f >> 6, c = f & 63;
        float4 x0 = *(const float4*)&hidden[(b0 + m) * U_N + c * 8];
        float4 x1 = *(const float4*)&hidden[(b0 + m) * U_N + c * 8 + 4];
        ushort tmp[8] = {f2bf(x0.x), f2bf(x0.y), f2bf(x0.z), f2bf(x0.w),
                         f2bf(x1.x), f2bf(x1.y), f2bf(x1.z), f2bf(x1.w)};
        *(uint4*)&As[(m * 64 + (c ^ (m & 7))) * 8] = *(uint4*)tmp;
    }
    __syncthreads();

    const int w = t >> 6, lane = t & 63;
    const int ml = lane & 15, q = lane >> 4;

    f32x4 acc[2];
#pragma unroll
    for (int nt = 0; nt < 2; ++nt) acc[nt] = (f32x4){0.f, 0.f, 0.f, 0.f};

    for (int ks = 0; ks < 16; ++ks) {
        int c = ks * 4 + q;
        bf16x8 a = *(const bf16x8*)&As[(ml * 64 + (c ^ (ml & 7))) * 8];
        bf16x8 bb[2];
#pragma unroll
        for (int nt = 0; nt < 2; ++nt) {
            int ntg = blockIdx.y * 8 + w * 2 + nt;
            bb[nt] = *(const bf16x8*)&W2p[(size_t)((ntg * 16 + ks) * 64 + lane) * 8];
        }
#pragma unroll
        for (int nt = 0; nt < 2; ++nt)
            acc[nt] = __builtin_amdgcn_mfma_f32_16x16x32_bf16(a, bb[nt], acc[nt], 0, 0, 0);
    }

    // C layout: n = nt*16 + ml (col), m = q*4 + r (row)
#pragma unroll
    for (int nt = 0; nt < 2; ++nt) {
        int n = u0 + (w * 2 + nt) * 16 + ml;
        float bias = b1[n] + b2[n];
#pragma unroll
        for (int r = 0; r < 4; ++r)
            ph[(size_t)(b0 + q * 4 + r) * U_N + n] = f2bf(acc[nt][r] + bias);
    }
}

// ---------------------------------------------------------------------------
// K2: per-batch fused attention, bf16 MFMA.
// uc=4 lean structure (acc[4][2]=32 AGPR) at __launch_bounds__(256,3):
// total reg cap ~168/wave; even with a 64-reg acc reservation, arch cap ~104
// exceeds the ~90-100 this structure needs -> expect NO spill + 12 waves/CU.
// (R3: uc2@4waves spilled; R4: uc2@2waves clean/130us; R5: uc4@4waves spilled.)
// ---------------------------------------------------------------------------
__global__ __launch_bounds__(256, 3) void attn_kernel(
    const float* __restrict__ features, const ushort* __restrict__ W1p,
    const float* __restrict__ V, const float* __restrict__ bV,
    const ushort* __restrict__ ph, float* __restrict__ out)
{
    __shared__ ushort As[64 * 256];   // 32 KB, chunk (m,c) at m*32 + (c ^ (m&31))
    __shared__ float lpart[4][64];
    __shared__ float wls[64];

    const int b    = blockIdx.x;
    const int t    = threadIdx.x;
    const int w    = t >> 6;
    const int lane = t & 63;
    const int ml   = lane & 15;
    const int q    = lane >> 4;
    const float* fb = features + (size_t)b * (L_N * D_N);

    // stage features -> bf16 swizzled LDS (2048 chunks, 8/thread)
#pragma unroll
    for (int i = 0; i < 8; ++i) {
        int f = t + i * 256;
        int m = f >> 5, c = f & 31;
        float4 x0 = *(const float4*)&fb[m * D_N + c * 8];
        float4 x1 = *(const float4*)&fb[m * D_N + c * 8 + 4];
        ushort tmp[8] = {f2bf(x0.x), f2bf(x0.y), f2bf(x0.z), f2bf(x0.w),
                         f2bf(x1.x), f2bf(x1.y), f2bf(x1.z), f2bf(x1.w)};
        *(uint4*)&As[(m * 32 + (c ^ (m & 31))) * 8] = *(uint4*)tmp;
    }
    __syncthreads();

    for (int uc = 0; uc < 4; ++uc) {
        f32x4 acc[4][2];
#pragma unroll
        for (int mt = 0; mt < 4; ++mt)
#pragma unroll
            for (int nt = 0; nt < 2; ++nt)
                acc[mt][nt] = (f32x4){0.f, 0.f, 0.f, 0.f};

        for (int ks = 0; ks < 8; ++ks) {
            bf16x8 a[4];
#pragma unroll
            for (int mt = 0; mt < 4; ++mt) {
                int m = mt * 16 + ml;
                int c = ks * 4 + q;
                a[mt] = *(const bf16x8*)&As[(m * 32 + (c ^ (m & 31))) * 8];
            }
            bf16x8 bf[2];
#pragma unroll
            for (int nt = 0; nt < 2; ++nt) {
                int chunk = ((w * 8 + uc * 2 + nt) * 8 + ks) * 64 + lane;
                bf[nt] = *(const bf16x8*)&W1p[(size_t)chunk * 8];
            }
#pragma unroll
            for (int nt = 0; nt < 2; ++nt)
#pragma unroll
                for (int mt = 0; mt < 4; ++mt)
                    acc[mt][nt] = __builtin_amdgcn_mfma_f32_16x16x32_bf16(
                        a[mt], bf[nt], acc[mt][nt], 0, 0, 0);
        }

        // epilogue for this 32-u chunk: tanh(C + ph) . V, n-lane reduce, fold.
        // D layout: n = nt*16 + ml, m = mt*16 + q*4 + r
        float lp[16];
#pragma unroll
        for (int j = 0; j < 16; ++j) lp[j] = 0.f;
#pragma unroll
        for (int nt = 0; nt < 2; ++nt) {
            int n = w * 128 + uc * 32 + nt * 16 + ml;
            float phv = bf2f(ph[(size_t)b * U_N + n]);
            float vv  = V[n];
#pragma unroll
            for (int mt = 0; mt < 4; ++mt)
#pragma unroll
                for (int r = 0; r < 4; ++r) {
                    float s = fast_tanh(acc[mt][nt][r] + phv);
                    lp[mt * 4 + r] = fmaf(s, vv, lp[mt * 4 + r]);
                }
        }
#pragma unroll
        for (int off = 1; off <= 8; off <<= 1)
#pragma unroll
            for (int j = 0; j < 16; ++j)
                lp[j] += __shfl_xor(lp[j], off);
        if (ml == 0) {
#pragma unroll
            for (int mt = 0; mt < 4; ++mt)
#pragma unroll
                for (int r = 0; r < 4; ++r) {
                    int m = mt * 16 + q * 4 + r;
                    if (uc == 0) lpart[w][m] = lp[mt * 4 + r];
                    else         lpart[w][m] += lp[mt * 4 + r];
                }
        }
    }
    __syncthreads();

    if (t < 64) {
        float lsum = bV[0] + lpart[0][t] + lpart[1][t] + lpart[2][t] + lpart[3][t];
        float mx = lsum;
#pragma unroll
        for (int off = 32; off > 0; off >>= 1)
            mx = fmaxf(mx, __shfl_xor(mx, off));
        float e = __expf(lsum - mx);
        float ssum = e;
#pragma unroll
        for (int off = 32; off > 0; off >>= 1)
            ssum += __shfl_xor(ssum, off);
        float wt = e / ssum;
        wls[t] = wt;
        out[(size_t)B_N * D_N + (size_t)b * L_N + t] = wt;
    }
    __syncthreads();

    float ctx = 0.f;
#pragma unroll 16
    for (int l = 0; l < L_N; ++l) {
        ushort u = As[(l * 32 + ((t >> 3) ^ (l & 31))) * 8 + (t & 7)];
        ctx = fmaf(wls[l], bf2f(u), ctx);
    }
    out[(size_t)b * D_N + t] = ctx;
}

// ---------------------------------------------------------------------------
extern "C" void kernel_launch(void* const* d_in, const int* in_sizes, int n_in,
                              void* d_out, int out_size, void* d_ws, size_t ws_size,
                              hipStream_t stream) {
    const float* features = (const float*)d_in[0];
    const float* hidden   = (const float*)d_in[1];
    const float* W1       = (const float*)d_in[2];
    const float* b1       = (const float*)d_in[3];
    const float* W2       = (const float*)d_in[4];
    const float* b2       = (const float*)d_in[5];
    const float* V        = (const float*)d_in[6];
    const float* bV       = (const float*)d_in[7];
    float* out = (float*)d_out;

    // ws: ph bf16 2 MB @0 | W1p 256 KB @2M | W2p 512 KB @2.25M
    ushort* ph  = (ushort*)d_ws;
    ushort* W1p = (ushort*)((char*)d_ws + (size_t)B_N * U_N * 2);
    ushort* W2p = (ushort*)((char*)d_ws + (size_t)B_N * U_N * 2 + (size_t)D_N * U_N * 2);

    pack_weights<<<192, 256, 0, stream>>>(W1, W2, W1p, W2p);
    proj_h_mfma<<<dim3(B_N / 16, U_N / 128), 256, 0, stream>>>(hidden, W2p, b1, b2, ph);
    attn_kernel<<<B_N, 256, 0, stream>>>(features, W1p, V, bV, ph, out);
}

// Round 7
// 305.804 us; speedup vs baseline: 1.1723x; 1.0985x over previous
//
#include <hip/hip_runtime.h>
#include <math.h>

#define B_N 2048
#define L_N 64
#define D_N 256   // EMBED_DIM
#define U_N 512   // UNITS

typedef __attribute__((ext_vector_type(8))) short bf16x8;   // 8 bf16 = 4 VGPRs
typedef __attribute__((ext_vector_type(4))) float f32x4;    // MFMA 16x16 acc

__device__ __forceinline__ float fast_tanh(float x) {
    float e = __expf(2.0f * x);
    return 1.0f - 2.0f / (e + 1.0f);
}
// fp32 -> bf16 round-to-nearest-even
__device__ __forceinline__ ushort f2bf(float x) {
    uint b = __float_as_uint(x);
    uint r = (b + 0x7FFF + ((b >> 16) & 1)) >> 16;
    return (ushort)r;
}
__device__ __forceinline__ float bf2f(ushort u) {
    uint v = ((uint)u) << 16;
    return __uint_as_float(v);
}

// ---------------------------------------------------------------------------
// K0: pack W1 [256,512] and W2 [512,512] fp32 -> bf16 MFMA B-fragment order.
// chunk g = (ntg*KS + ks)*64 + lane holds W[ks*32 + (lane>>4)*8 + j][ntg*16 + (lane&15)]
// ---------------------------------------------------------------------------
__global__ __launch_bounds__(256) void pack_weights(
    const float* __restrict__ W1, const float* __restrict__ W2,
    ushort* __restrict__ W1p, ushort* __restrict__ W2p)
{
    ushort tmp[8];
    if (blockIdx.x < 64) {
        int g = blockIdx.x * 256 + threadIdx.x;      // 0..16383
        int ntg = g >> 9, ks = (g >> 6) & 7, lane = g & 63;
        int n  = ntg * 16 + (lane & 15);
        int kb = ks * 32 + (lane >> 4) * 8;
#pragma unroll
        for (int j = 0; j < 8; ++j) tmp[j] = f2bf(W1[(kb + j) * U_N + n]);
        *(uint4*)&W1p[(size_t)g * 8] = *(uint4*)tmp;
    } else {
        int g = (blockIdx.x - 64) * 256 + threadIdx.x;  // 0..32767
        int ntg = g >> 10, ks = (g >> 6) & 15, lane = g & 63;
        int n  = ntg * 16 + (lane & 15);
        int kb = ks * 32 + (lane >> 4) * 8;
#pragma unroll
        for (int j = 0; j < 8; ++j) tmp[j] = f2bf(W2[(kb + j) * U_N + n]);
        *(uint4*)&W2p[(size_t)g * 8] = *(uint4*)tmp;
    }
}

// ---------------------------------------------------------------------------
// K1: ph = hidden @ W2 + b1 + b2 via bf16 MFMA, stored bf16.
// grid (B/16, U/128) = (128,4) = 512 blocks (2/CU). Wave: 32 u (2 n-tiles).
// ---------------------------------------------------------------------------
__global__ __launch_bounds__(256) void proj_h_mfma(
    const float* __restrict__ hidden, const ushort* __restrict__ W2p,
    const float* __restrict__ b1, const float* __restrict__ b2,
    ushort* __restrict__ ph)
{
    __shared__ ushort As[16 * 512];   // 16 KB

    const int t  = threadIdx.x;
    const int b0 = blockIdx.x * 16;
    const int u0 = blockIdx.y * 128;

    // stage hidden 16x512 fp32 -> bf16 (1024 chunks of 8, 4/thread), swizzled
#pragma unroll
    for (int i = 0; i < 4; ++i) {
        int f = t + i * 256;
        int m = f >> 6, c = f & 63;
        float4 x0 = *(const float4*)&hidden[(b0 + m) * U_N + c * 8];
        float4 x1 = *(const float4*)&hidden[(b0 + m) * U_N + c * 8 + 4];
        ushort tmp[8] = {f2bf(x0.x), f2bf(x0.y), f2bf(x0.z), f2bf(x0.w),
                         f2bf(x1.x), f2bf(x1.y), f2bf(x1.z), f2bf(x1.w)};
        *(uint4*)&As[(m * 64 + (c ^ (m & 7))) * 8] = *(uint4*)tmp;
    }
    __syncthreads();

    const int w = t >> 6, lane = t & 63;
    const int ml = lane & 15, q = lane >> 4;

    f32x4 acc[2];
#pragma unroll
    for (int nt = 0; nt < 2; ++nt) acc[nt] = (f32x4){0.f, 0.f, 0.f, 0.f};

    for (int ks = 0; ks < 16; ++ks) {
        int c = ks * 4 + q;
        bf16x8 a = *(const bf16x8*)&As[(ml * 64 + (c ^ (ml & 7))) * 8];
        bf16x8 bb[2];
#pragma unroll
        for (int nt = 0; nt < 2; ++nt) {
            int ntg = blockIdx.y * 8 + w * 2 + nt;
            bb[nt] = *(const bf16x8*)&W2p[(size_t)((ntg * 16 + ks) * 64 + lane) * 8];
        }
#pragma unroll
        for (int nt = 0; nt < 2; ++nt)
            acc[nt] = __builtin_amdgcn_mfma_f32_16x16x32_bf16(a, bb[nt], acc[nt], 0, 0, 0);
    }

    // C layout: n = nt*16 + ml (col), m = q*4 + r (row)
#pragma unroll
    for (int nt = 0; nt < 2; ++nt) {
        int n = u0 + (w * 2 + nt) * 16 + ml;
        float bias = b1[n] + b2[n];
#pragma unroll
        for (int r = 0; r < 4; ++r)
            ph[(size_t)(b0 + q * 4 + r) * U_N + n] = f2bf(acc[nt][r] + bias);
    }
}

// ---------------------------------------------------------------------------
// K2: per-batch fused attention, bf16 MFMA, register-LEAN tiling.
// Wave w owns 32 l's (wl=w&1 -> 2 m-tiles) x 256 u (uhw=w>>1), in EIGHT 32-u
// chunks: acc[2][2]=16 AGPR, a[2]+bf[2]=16 VGPR, logit partials lp[8] persist
// in regs across chunks (ONE shuffle-reduce at end). Natural alloc target
// ~90 arch + 16 acc => 3-4 waves/SIMD WITHOUT launch-bounds forcing
// (R3/R5/R6: any forced min-waves>=3 spilled; R4 natural=192 -> 2 waves).
// Context re-reads features fp32 from global (L3-hot) - no scalar LDS chain.
// ---------------------------------------------------------------------------
__global__ __launch_bounds__(256) void attn_kernel(
    const float* __restrict__ features, const ushort* __restrict__ W1p,
    const float* __restrict__ V, const float* __restrict__ bV,
    const ushort* __restrict__ ph, float* __restrict__ out)
{
    __shared__ ushort As[64 * 256];   // 32 KB, chunk (m,c) at m*32 + (c ^ (m&31))
    __shared__ float lpartU[2][64];   // per-u-half logit partials
    __shared__ float wls[64];

    const int b    = blockIdx.x;
    const int t    = threadIdx.x;
    const int w    = t >> 6;
    const int lane = t & 63;
    const int ml   = lane & 15;
    const int q    = lane >> 4;
    const int wl   = w & 1;          // l-half: m-tiles {wl*2, wl*2+1}
    const int uhw  = w >> 1;         // u-half: u in [uhw*256, uhw*256+256)
    const float* fb = features + (size_t)b * (L_N * D_N);

    // stage features -> bf16 swizzled LDS (2048 chunks, 8/thread)
#pragma unroll
    for (int i = 0; i < 8; ++i) {
        int f = t + i * 256;
        int m = f >> 5, c = f & 31;
        float4 x0 = *(const float4*)&fb[m * D_N + c * 8];
        float4 x1 = *(const float4*)&fb[m * D_N + c * 8 + 4];
        ushort tmp[8] = {f2bf(x0.x), f2bf(x0.y), f2bf(x0.z), f2bf(x0.w),
                         f2bf(x1.x), f2bf(x1.y), f2bf(x1.z), f2bf(x1.w)};
        *(uint4*)&As[(m * 32 + (c ^ (m & 31))) * 8] = *(uint4*)tmp;
    }
    __syncthreads();

    float lp[8];
#pragma unroll
    for (int j = 0; j < 8; ++j) lp[j] = 0.f;

    for (int uc = 0; uc < 8; ++uc) {
        f32x4 acc[2][2];
#pragma unroll
        for (int mt = 0; mt < 2; ++mt)
#pragma unroll
            for (int nt = 0; nt < 2; ++nt)
                acc[mt][nt] = (f32x4){0.f, 0.f, 0.f, 0.f};

        for (int ks = 0; ks < 8; ++ks) {
            bf16x8 a[2];
#pragma unroll
            for (int mt = 0; mt < 2; ++mt) {
                int m = (wl * 2 + mt) * 16 + ml;
                int c = ks * 4 + q;
                a[mt] = *(const bf16x8*)&As[(m * 32 + (c ^ (m & 31))) * 8];
            }
            bf16x8 bf[2];
#pragma unroll
            for (int nt = 0; nt < 2; ++nt) {
                int ntg = uhw * 16 + uc * 2 + nt;
                bf[nt] = *(const bf16x8*)&W1p[(size_t)((ntg * 8 + ks) * 64 + lane) * 8];
            }
#pragma unroll
            for (int nt = 0; nt < 2; ++nt)
#pragma unroll
                for (int mt = 0; mt < 2; ++mt)
                    acc[mt][nt] = __builtin_amdgcn_mfma_f32_16x16x32_bf16(
                        a[mt], bf[nt], acc[mt][nt], 0, 0, 0);
        }

        // fold this 32-u chunk into persistent lp.  D: n=nt*16+ml, m=mt*16+q*4+r
#pragma unroll
        for (int nt = 0; nt < 2; ++nt) {
            int n = uhw * 256 + uc * 32 + nt * 16 + ml;
            float phv = bf2f(ph[(size_t)b * U_N + n]);
            float vv  = V[n];
#pragma unroll
            for (int mt = 0; mt < 2; ++mt)
#pragma unroll
                for (int r = 0; r < 4; ++r) {
                    float s = fast_tanh(acc[mt][nt][r] + phv);
                    lp[mt * 4 + r] = fmaf(s, vv, lp[mt * 4 + r]);
                }
        }
    }

    // one shuffle-reduce over the 16 n-lanes (xor 1,2,4,8 stays within q-group)
#pragma unroll
    for (int off = 1; off <= 8; off <<= 1)
#pragma unroll
        for (int j = 0; j < 8; ++j)
            lp[j] += __shfl_xor(lp[j], off);
    if (ml == 0) {
#pragma unroll
        for (int mt = 0; mt < 2; ++mt)
#pragma unroll
            for (int r = 0; r < 4; ++r)
                lpartU[uhw][wl * 32 + mt * 16 + q * 4 + r] = lp[mt * 4 + r];
    }
    __syncthreads();

    if (t < 64) {
        float lsum = bV[0] + lpartU[0][t] + lpartU[1][t];
        float mx = lsum;
#pragma unroll
        for (int off = 32; off > 0; off >>= 1)
            mx = fmaxf(mx, __shfl_xor(mx, off));
        float e = __expf(lsum - mx);
        float ssum = e;
#pragma unroll
        for (int off = 32; off > 0; off >>= 1)
            ssum += __shfl_xor(ssum, off);
        float wt = e / ssum;
        wls[t] = wt;
        out[(size_t)B_N * D_N + (size_t)b * L_N + t] = wt;
    }
    __syncthreads();

    // context[d] = sum_l w_l * f[l][d], fp32 from global (L3-hot, coalesced)
    float ctx = 0.f;
#pragma unroll 8
    for (int l = 0; l < L_N; ++l)
        ctx = fmaf(wls[l], fb[l * D_N + t], ctx);
    out[(size_t)b * D_N + t] = ctx;
}

// ---------------------------------------------------------------------------
extern "C" void kernel_launch(void* const* d_in, const int* in_sizes, int n_in,
                              void* d_out, int out_size, void* d_ws, size_t ws_size,
                              hipStream_t stream) {
    const float* features = (const float*)d_in[0];
    const float* hidden   = (const float*)d_in[1];
    const float* W1       = (const float*)d_in[2];
    const float* b1       = (const float*)d_in[3];
    const float* W2       = (const float*)d_in[4];
    const float* b2       = (const float*)d_in[5];
    const float* V        = (const float*)d_in[6];
    const float* bV       = (const float*)d_in[7];
    float* out = (float*)d_out;

    // ws: ph bf16 2 MB @0 | W1p 256 KB @2M | W2p 512 KB @2.25M
    ushort* ph  = (ushort*)d_ws;
    ushort* W1p = (ushort*)((char*)d_ws + (size_t)B_N * U_N * 2);
    ushort* W2p = (ushort*)((char*)d_ws + (size_t)B_N * U_N * 2 + (size_t)D_N * U_N * 2);

    pack_weights<<<192, 256, 0, stream>>>(W1, W2, W1p, W2p);
    proj_h_mfma<<<dim3(B_N / 16, U_N / 128), 256, 0, stream>>>(hidden, W2p, b1, b2, ph);
    attn_kernel<<<B_N, 256, 0, stream>>>(features, W1p, V, bV, ph, out);
}

// Round 8
// 266.079 us; speedup vs baseline: 1.3474x; 1.1493x over previous
//
#include <hip/hip_runtime.h>
#include <math.h>

#define B_N 2048
#define L_N 64
#define D_N 256   // EMBED_DIM
#define U_N 512   // UNITS

typedef __attribute__((ext_vector_type(8))) short bf16x8;   // 8 bf16 = 4 VGPRs
typedef __attribute__((ext_vector_type(4))) float f32x4;    // MFMA 16x16 acc

// tanh(x) = 1 - 2/(2^(x*2*log2e)+1); v_mul+v_exp+v_add+v_rcp+v_fma
__device__ __forceinline__ float fast_tanh(float x) {
    float e = __builtin_amdgcn_exp2f(x * 2.8853900817779268f);
    float r = __builtin_amdgcn_rcpf(e + 1.0f);
    return fmaf(-2.0f, r, 1.0f);
}
// fp32 -> bf16 round-to-nearest-even
__device__ __forceinline__ ushort f2bf(float x) {
    uint b = __float_as_uint(x);
    uint r = (b + 0x7FFF + ((b >> 16) & 1)) >> 16;
    return (ushort)r;
}
__device__ __forceinline__ float bf2f(ushort u) {
    uint v = ((uint)u) << 16;
    return __uint_as_float(v);
}

// ---------------------------------------------------------------------------
// K0: pack W1 [256,512] and W2 [512,512] fp32 -> bf16 MFMA B-fragment order.
// chunk g = (ntg*KS + ks)*64 + lane holds W[ks*32 + (lane>>4)*8 + j][ntg*16 + (lane&15)]
// ---------------------------------------------------------------------------
__global__ __launch_bounds__(256) void pack_weights(
    const float* __restrict__ W1, const float* __restrict__ W2,
    ushort* __restrict__ W1p, ushort* __restrict__ W2p)
{
    ushort tmp[8];
    if (blockIdx.x < 64) {
        int g = blockIdx.x * 256 + threadIdx.x;      // 0..16383
        int ntg = g >> 9, ks = (g >> 6) & 7, lane = g & 63;
        int n  = ntg * 16 + (lane & 15);
        int kb = ks * 32 + (lane >> 4) * 8;
#pragma unroll
        for (int j = 0; j < 8; ++j) tmp[j] = f2bf(W1[(kb + j) * U_N + n]);
        *(uint4*)&W1p[(size_t)g * 8] = *(uint4*)tmp;
    } else {
        int g = (blockIdx.x - 64) * 256 + threadIdx.x;  // 0..32767
        int ntg = g >> 10, ks = (g >> 6) & 15, lane = g & 63;
        int n  = ntg * 16 + (lane & 15);
        int kb = ks * 32 + (lane >> 4) * 8;
#pragma unroll
        for (int j = 0; j < 8; ++j) tmp[j] = f2bf(W2[(kb + j) * U_N + n]);
        *(uint4*)&W2p[(size_t)g * 8] = *(uint4*)tmp;
    }
}

// ---------------------------------------------------------------------------
// K1: ph = hidden @ W2 + b1 + b2 via bf16 MFMA, stored bf16.
// grid (B/16, U/128) = (128,4) = 512 blocks (2/CU). Wave: 32 u (2 n-tiles).
// ---------------------------------------------------------------------------
__global__ __launch_bounds__(256) void proj_h_mfma(
    const float* __restrict__ hidden, const ushort* __restrict__ W2p,
    const float* __restrict__ b1, const float* __restrict__ b2,
    ushort* __restrict__ ph)
{
    __shared__ ushort As[16 * 512];   // 16 KB

    const int t  = threadIdx.x;
    const int b0 = blockIdx.x * 16;
    const int u0 = blockIdx.y * 128;

    // stage hidden 16x512 fp32 -> bf16 (1024 chunks of 8, 4/thread), swizzled
#pragma unroll
    for (int i = 0; i < 4; ++i) {
        int f = t + i * 256;
        int m = f >> 6, c = f & 63;
        float4 x0 = *(const float4*)&hidden[(b0 + m) * U_N + c * 8];
        float4 x1 = *(const float4*)&hidden[(b0 + m) * U_N + c * 8 + 4];
        ushort tmp[8] = {f2bf(x0.x), f2bf(x0.y), f2bf(x0.z), f2bf(x0.w),
                         f2bf(x1.x), f2bf(x1.y), f2bf(x1.z), f2bf(x1.w)};
        *(uint4*)&As[(m * 64 + (c ^ (m & 7))) * 8] = *(uint4*)tmp;
    }
    __syncthreads();

    const int w = t >> 6, lane = t & 63;
    const int ml = lane & 15, q = lane >> 4;

    f32x4 acc[2];
#pragma unroll
    for (int nt = 0; nt < 2; ++nt) acc[nt] = (f32x4){0.f, 0.f, 0.f, 0.f};

    for (int ks = 0; ks < 16; ++ks) {
        int c = ks * 4 + q;
        bf16x8 a = *(const bf16x8*)&As[(ml * 64 + (c ^ (ml & 7))) * 8];
        bf16x8 bb[2];
#pragma unroll
        for (int nt = 0; nt < 2; ++nt) {
            int ntg = blockIdx.y * 8 + w * 2 + nt;
            bb[nt] = *(const bf16x8*)&W2p[(size_t)((ntg * 16 + ks) * 64 + lane) * 8];
        }
#pragma unroll
        for (int nt = 0; nt < 2; ++nt)
            acc[nt] = __builtin_amdgcn_mfma_f32_16x16x32_bf16(a, bb[nt], acc[nt], 0, 0, 0);
    }

    // C layout: n = nt*16 + ml (col), m = q*4 + r (row)
#pragma unroll
    for (int nt = 0; nt < 2; ++nt) {
        int n = u0 + (w * 2 + nt) * 16 + ml;
        float bias = b1[n] + b2[n];
#pragma unroll
        for (int r = 0; r < 4; ++r)
            ph[(size_t)(b0 + q * 4 + r) * U_N + n] = f2bf(acc[nt][r] + bias);
    }
}

// ---------------------------------------------------------------------------
// K2: per-batch fused attention, bf16 MFMA.
// R4 tile shape (wave = 64l x 128u strip, uc=4 chunks of 32u, acc[4][2]=32
// AGPR, 4:1 MFMA:B-load) + R7 persistent lp[16] (one shuffle-reduce at end)
// + 2-deep B-frag double buffer in ks loop. NATURAL allocation (no min-waves:
// R3/R5/R6 showed any forced cap >=3 spills). Est ~105 arch + 32 acc.
// ---------------------------------------------------------------------------
__global__ __launch_bounds__(256) void attn_kernel(
    const float* __restrict__ features, const ushort* __restrict__ W1p,
    const float* __restrict__ V, const float* __restrict__ bV,
    const ushort* __restrict__ ph, float* __restrict__ out)
{
    __shared__ ushort As[64 * 256];   // 32 KB, chunk (m,c) at m*32 + (c ^ (m&31))
    __shared__ float lpart[4][64];
    __shared__ float wls[64];

    const int b    = blockIdx.x;
    const int t    = threadIdx.x;
    const int w    = t >> 6;
    const int lane = t & 63;
    const int ml   = lane & 15;
    const int q    = lane >> 4;
    const float* fb = features + (size_t)b * (L_N * D_N);

    // stage features -> bf16 swizzled LDS (2048 chunks, 8/thread)
#pragma unroll
    for (int i = 0; i < 8; ++i) {
        int f = t + i * 256;
        int m = f >> 5, c = f & 31;
        float4 x0 = *(const float4*)&fb[m * D_N + c * 8];
        float4 x1 = *(const float4*)&fb[m * D_N + c * 8 + 4];
        ushort tmp[8] = {f2bf(x0.x), f2bf(x0.y), f2bf(x0.z), f2bf(x0.w),
                         f2bf(x1.x), f2bf(x1.y), f2bf(x1.z), f2bf(x1.w)};
        *(uint4*)&As[(m * 32 + (c ^ (m & 31))) * 8] = *(uint4*)tmp;
    }
    __syncthreads();

    float lp[16];
#pragma unroll
    for (int j = 0; j < 16; ++j) lp[j] = 0.f;

    const ushort* W1w = W1p + (size_t)(w * 8) * 8 * 64 * 8;  // wave's 128-u strip

    for (int uc = 0; uc < 4; ++uc) {
        f32x4 acc[4][2];
#pragma unroll
        for (int mt = 0; mt < 4; ++mt)
#pragma unroll
            for (int nt = 0; nt < 2; ++nt)
                acc[mt][nt] = (f32x4){0.f, 0.f, 0.f, 0.f};

        // B-frag double buffer: load ks=0 pair up front
        bf16x8 bfc[2], bfn[2];
#pragma unroll
        for (int nt = 0; nt < 2; ++nt)
            bfc[nt] = *(const bf16x8*)&W1w[(size_t)(((uc * 2 + nt) * 8 + 0) * 64 + lane) * 8];

        for (int ks = 0; ks < 8; ++ks) {
            if (ks < 7) {
#pragma unroll
                for (int nt = 0; nt < 2; ++nt)
                    bfn[nt] = *(const bf16x8*)&W1w[(size_t)(((uc * 2 + nt) * 8 + ks + 1) * 64 + lane) * 8];
            }
            bf16x8 a[4];
#pragma unroll
            for (int mt = 0; mt < 4; ++mt) {
                int m = mt * 16 + ml;
                int c = ks * 4 + q;
                a[mt] = *(const bf16x8*)&As[(m * 32 + (c ^ (m & 31))) * 8];
            }
#pragma unroll
            for (int nt = 0; nt < 2; ++nt)
#pragma unroll
                for (int mt = 0; mt < 4; ++mt)
                    acc[mt][nt] = __builtin_amdgcn_mfma_f32_16x16x32_bf16(
                        a[mt], bfc[nt], acc[mt][nt], 0, 0, 0);
            bfc[0] = bfn[0]; bfc[1] = bfn[1];
        }

        // fold this 32-u chunk into persistent lp.  D: n=nt*16+ml, m=mt*16+q*4+r
#pragma unroll
        for (int nt = 0; nt < 2; ++nt) {
            int n = w * 128 + uc * 32 + nt * 16 + ml;
            float phv = bf2f(ph[(size_t)b * U_N + n]);
            float vv  = V[n];
#pragma unroll
            for (int mt = 0; mt < 4; ++mt)
#pragma unroll
                for (int r = 0; r < 4; ++r) {
                    float s = fast_tanh(acc[mt][nt][r] + phv);
                    lp[mt * 4 + r] = fmaf(s, vv, lp[mt * 4 + r]);
                }
        }
    }

    // one shuffle-reduce over the 16 n-lanes (xor 1,2,4,8 stays within q-group)
#pragma unroll
    for (int off = 1; off <= 8; off <<= 1)
#pragma unroll
        for (int j = 0; j < 16; ++j)
            lp[j] += __shfl_xor(lp[j], off);
    if (ml == 0) {
#pragma unroll
        for (int mt = 0; mt < 4; ++mt)
#pragma unroll
            for (int r = 0; r < 4; ++r)
                lpart[w][mt * 16 + q * 4 + r] = lp[mt * 4 + r];
    }
    __syncthreads();

    if (t < 64) {
        float lsum = bV[0] + lpart[0][t] + lpart[1][t] + lpart[2][t] + lpart[3][t];
        float mx = lsum;
#pragma unroll
        for (int off = 32; off > 0; off >>= 1)
            mx = fmaxf(mx, __shfl_xor(mx, off));
        float e = __expf(lsum - mx);
        float ssum = e;
#pragma unroll
        for (int off = 32; off > 0; off >>= 1)
            ssum += __shfl_xor(ssum, off);
        float wt = e / ssum;
        wls[t] = wt;
        out[(size_t)B_N * D_N + (size_t)b * L_N + t] = wt;
    }
    __syncthreads();

    // context[d] = sum_l w_l * f[l][d], from LDS bf16 (t == d)
    float ctx = 0.f;
#pragma unroll 16
    for (int l = 0; l < L_N; ++l) {
        ushort u = As[(l * 32 + ((t >> 3) ^ (l & 31))) * 8 + (t & 7)];
        ctx = fmaf(wls[l], bf2f(u), ctx);
    }
    out[(size_t)b * D_N + t] = ctx;
}

// ---------------------------------------------------------------------------
extern "C" void kernel_launch(void* const* d_in, const int* in_sizes, int n_in,
                              void* d_out, int out_size, void* d_ws, size_t ws_size,
                              hipStream_t stream) {
    const float* features = (const float*)d_in[0];
    const float* hidden   = (const float*)d_in[1];
    const float* W1       = (const float*)d_in[2];
    const float* b1       = (const float*)d_in[3];
    const float* W2       = (const float*)d_in[4];
    const float* b2       = (const float*)d_in[5];
    const float* V        = (const float*)d_in[6];
    const float* bV       = (const float*)d_in[7];
    float* out = (float*)d_out;

    // ws: ph bf16 2 MB @0 | W1p 256 KB @2M | W2p 512 KB @2.25M
    ushort* ph  = (ushort*)d_ws;
    ushort* W1p = (ushort*)((char*)d_ws + (size_t)B_N * U_N * 2);
    ushort* W2p = (ushort*)((char*)d_ws + (size_t)B_N * U_N * 2 + (size_t)D_N * U_N * 2);

    pack_weights<<<192, 256, 0, stream>>>(W1, W2, W1p, W2p);
    proj_h_mfma<<<dim3(B_N / 16, U_N / 128), 256, 0, stream>>>(hidden, W2p, b1, b2, ph);
    attn_kernel<<<B_N, 256, 0, stream>>>(features, W1p, V, bV, ph, out);
}